// Round 9
// baseline (213.323 us; speedup 1.0000x reference)
//
#include <hip/hip_runtime.h>

// GaussianHistogram: hist[b,i,j] = sum_n exp(-pi*(u1-i)^2) * exp(-pi*(u2-j)^2) * mask
// u = (x - MIN_V)/DELTA - 0.5 ; COEF == 1.0 exactly.
//
// v9: ONE plain dispatch, spin-free ticket merge (no cooperative launch).
// Evidence v8: grid.sync() cost ~106us idle (VALUBusy 4.4% over 111us) + ~31us
// cooperative-launch overhead -> cooperative path dead. Model fit v1-v8:
// dur ~= 41us harness ws-fill + ~12-15us per dispatch boundary + kernel work
// (VALU is tiny: ~5us for 8192 evals/CU, measured v8).
// So: minimize BOTH boundaries (1 dispatch) and evals/CU (8192).
//
// Structure: 512 blocks (2/CU) = (batch 8) x (32-row tile 8) x (point-chunk 8).
// Each block scans its 4096-pt chunk, deposits owned-row taps into a 32KB LDS
// partial tile (v5/v6 packing, passed absmax 0.0156), stores partial to ws,
// then: __threadfence (release: L2 writeback) -> atomicAdd on the group's
// __device__ ticket counter. The 8th arriver per (b,t) group (ticket&7==7;
// counters are zero-init device globals that only increment -> modulo is
// correct across warmup/timed/rocprof replays) acquires (__threadfence) and
// reduces the 8 partials -> out rows. No spin, no wait, deadlock-free.
// Cross-XCD visibility: identical fence pattern v8 proved correct.
//
// Deposit math (= v5/v6/v8): 3 exact row taps x one 4-col 16-bit-field u64
// word; two phase-shifted packings (phase0 words cols 4w.., phase1 4w+2..) so
// the col window [j0-1,j0+1] fits one word; 4th field = exact bonus tap.
// Dropped taps >=1.5 bins (w <= 8.5e-4). .10 fixed point; per-chunk per-field
// max ~8 pts * 1024 << 65535 -> no cross-field carry.
// Exp factorization (4 exp + 2 rcp per eval): rows w0*K^{a^2}*E^{-a}; cols
// P*Q^{3,1,-1,-3}*{C2,C1,C1,C2}, s=t2-1.5.

#define BINS   256
#define NPTS   32768
#define BATCH  8
#define TROWS  32                  // rows per tile
#define NTILE  (BINS / TROWS)      // 8
#define CHUNK  8                   // point chunks per batch
#define PPB    (NPTS / CHUNK)      // 4096 points per block
#define WORDS  64                  // u64 words per row per phase
#define TILE64 (2 * TROWS * WORDS) // 4096 u64 = 32 KB
#define NBLK   (BATCH * NTILE * CHUNK) // 512 blocks, 2/CU

static constexpr float kInvDelta = 256.0f / 1.5f;                  // 1/DELTA
static constexpr float kUAdd     = 0.25f * (256.0f / 1.5f) - 0.5f; // (x-MIN)/D - 0.5
static constexpr float kPi       = 3.14159265358979323846f;
static constexpr float kTwoPi    = 6.28318530717958647692f;
static constexpr float kEmPi     = 0.043213918263772250f;   // exp(-pi)
static constexpr float kC1       = 0.4559381277659962f;     // exp(-0.25*pi)
static constexpr float kC2       = 8.514366756432101e-4f;   // exp(-2.25*pi)
static constexpr float kFix      = 1024.0f;                 // .10 fixed point
static constexpr float kInvFix   = 1.0f / 1024.0f;

__device__ unsigned gTick[BATCH * NTILE];   // zero-init; increments only

__global__ __launch_bounds__(512, 4) void gh_fused(
    const float* __restrict__ x1, const float* __restrict__ x2,
    const float* __restrict__ mask, unsigned long long* __restrict__ ws,
    float* __restrict__ out)
{
    __shared__ unsigned long long tile[TILE64];   // 32 KB
    __shared__ int sLast;
    const int tid = threadIdx.x;
    const int blk = blockIdx.x;
    const int b   = blk >> 6;
    const int t   = (blk >> 3) & 7;
    const int z   = blk & 7;
    const int r0  = t * TROWS;
    const int grp = b * NTILE + t;

    // ---------------- phase A: scatter chunk z into LDS partial tile --------
#pragma unroll
    for (int i = tid; i < TILE64; i += 512) tile[i] = 0ULL;
    __syncthreads();

    const float4* X1 = (const float4*)(x1   + b * NPTS + z * PPB);
    const float4* X2 = (const float4*)(x2   + b * NPTS + z * PPB);
    const float4* M  = (const float4*)(mask + b * NPTS + z * PPB);

#pragma unroll
    for (int it = 0; it < PPB / 2048; ++it) {     // 2 iterations, 4 points each
        const int n4 = it * 512 + tid;
        const float4 a4 = X1[n4];
        const float4 b4 = X2[n4];
        const float4 m4 = M[n4];

        const float pv1[4] = {a4.x, a4.y, a4.z, a4.w};
        const float pv2[4] = {b4.x, b4.y, b4.z, b4.w};
        const float pm[4]  = {m4.x, m4.y, m4.z, m4.w};

#pragma unroll
        for (int k = 0; k < 4; ++k) {
            const float u1 = fmaf(pv1[k], kInvDelta, kUAdd);
            const float u2 = fmaf(pv2[k], kInvDelta, kUAdd);
            const float fi = rintf(u1);
            int i0 = (int)fi;
            i0 = min(254, max(1, i0));
            const float t1 = u1 - fi;              // [-0.5, 0.5]

            int e = (((int)rintf(u2)) - 1) & ~1;
            e = min(250, max(0, e));
            const int  ph   = (e >> 1) & 1;
            const int  word = e >> 2;
            const float s   = (u2 - (float)e) - 1.5f;  // [-1, 1]

            // row weights via factorization
            const float w0  = __expf(-kPi * t1 * t1);
            const float E   = __expf(-kTwoPi * t1);
            const float iE  = __builtin_amdgcn_rcpf(E);
            const float w0K = w0 * kEmPi;
            const float wr0 = w0K * E;
            const float wr2 = w0K * iE;

            // col weights via factorization (mask + fixed scale folded in)
            const float P   = __expf(-kPi * s * s);
            const float Q   = __expf(-kPi * s);
            const float iQ  = __builtin_amdgcn_rcpf(Q);
            const float Q3  = Q * Q * Q;
            const float iQ3 = iQ * iQ * iQ;
            const float pmF = pm[k] * kFix;
            const float PC1 = P * (kC1 * pmF);
            const float PC2 = P * (kC2 * pmF);
            const float W0 = PC2 * Q3, W1 = PC1 * Q, W2v = PC1 * iQ, W3 = PC2 * iQ3;

            const int rbase = i0 - 1 - r0;
            const int pbase = ph * (TROWS * WORDS) + word;
            const float wra[3] = {wr0, w0, wr2};
#pragma unroll
            for (int a = 0; a < 3; ++a) {
                const int r = rbase + a;
                if ((unsigned)r < TROWS) {
                    const float wa = wra[a];
                    const unsigned f0 = (unsigned)fmaf(wa, W0, 0.5f);
                    const unsigned f1 = (unsigned)fmaf(wa, W1, 0.5f);
                    const unsigned f2 = (unsigned)fmaf(wa, W2v, 0.5f);
                    const unsigned f3 = (unsigned)fmaf(wa, W3, 0.5f);
                    const unsigned long long w =
                        (unsigned long long)(f0 | (f1 << 16)) |
                        ((unsigned long long)(f2 | (f3 << 16)) << 32);
                    atomicAdd(&tile[pbase + r * WORDS], w);   // ds_add_u64
                }
            }
        }
    }
    __syncthreads();

    // ---------------- store partial, release, take ticket -------------------
    {
        unsigned long long* W = ws + (size_t)blk * TILE64;
#pragma unroll
        for (int i = tid; i < TILE64; i += 512) W[i] = tile[i];
    }
    __threadfence();                  // release: drain + L2 writeback
    __syncthreads();                  // all waves' fences complete
    if (tid == 0)
        sLast = ((atomicAdd(&gTick[grp], 1u) & (CHUNK - 1)) == (CHUNK - 1));
    __syncthreads();
    if (!sLast) return;
    __threadfence();                  // acquire: invalidate stale caches

    // ---------------- phase B (last arriver only): reduce group -> out ------
    const unsigned long long* G = ws + (size_t)grp * CHUNK * TILE64;
#pragma unroll
    for (int widx = tid; widx < TROWS * WORDS; widx += 512) {  // 4 iters
        const int row = widx >> 6;
        const int w   = widx & 63;
        unsigned s00 = 0, s01 = 0, s02 = 0, s03 = 0;   // phase0 word w
        unsigned p2 = 0, p3 = 0;                       // phase1 word w-1, fields 2,3
        unsigned c0 = 0, c1 = 0;                       // phase1 word w, fields 0,1
#pragma unroll
        for (int zz = 0; zz < CHUNK; ++zz) {
            const unsigned long long* Zp = G + (size_t)zz * TILE64;
            const unsigned long long w0 = Zp[row * WORDS + w];
            s00 += (unsigned)(w0)       & 0xFFFFu;
            s01 += (unsigned)(w0 >> 16) & 0xFFFFu;
            s02 += (unsigned)(w0 >> 32) & 0xFFFFu;
            s03 += (unsigned)(w0 >> 48) & 0xFFFFu;
            const unsigned long long w1c = Zp[TROWS * WORDS + row * WORDS + w];
            c0 += (unsigned)(w1c)       & 0xFFFFu;
            c1 += (unsigned)(w1c >> 16) & 0xFFFFu;
            if (w > 0) {
                const unsigned long long w1p = Zp[TROWS * WORDS + row * WORDS + w - 1];
                p2 += (unsigned)(w1p >> 32) & 0xFFFFu;
                p3 += (unsigned)(w1p >> 48) & 0xFFFFu;
            }
        }
        float4 o;
        o.x = (float)(s00 + p2) * kInvFix;   // col 4w   : p0 f0 + p1[w-1] f2
        o.y = (float)(s01 + p3) * kInvFix;   // col 4w+1 : p0 f1 + p1[w-1] f3
        o.z = (float)(s02 + c0) * kInvFix;   // col 4w+2 : p0 f2 + p1[w] f0
        o.w = (float)(s03 + c1) * kInvFix;   // col 4w+3 : p0 f3 + p1[w] f1
        *(float4*)(out + ((size_t)b * BINS + r0 + row) * BINS + 4 * w) = o;
    }
}

extern "C" void kernel_launch(void* const* d_in, const int* in_sizes, int n_in,
                              void* d_out, int out_size, void* d_ws, size_t ws_size,
                              hipStream_t stream) {
    const float* x1   = (const float*)d_in[0];
    const float* x2   = (const float*)d_in[1];
    const float* mask = (const float*)d_in[2];
    float*       out  = (float*)d_out;
    unsigned long long* ws = (unsigned long long*)d_ws;

    gh_fused<<<dim3(NBLK), 512, 0, stream>>>(x1, x2, mask, ws, out);
}

// Round 10
// 75.919 us; speedup vs baseline: 2.8099x; 2.8099x over previous
//
#include <hip/hip_runtime.h>

// GaussianHistogram: hist[b,i,j] = sum_n exp(-pi*(u1-i)^2) * exp(-pi*(u2-j)^2) * mask
// u = (x - MIN_V)/DELTA - 0.5 ; COEF == 1.0 exactly.
//
// v10: SINGLE-TOUCH two-dispatch. Evidence summary v1-v9:
//  - in-kernel device sync dead: grid.sync ~106us idle (v8), threadfence+ticket
//    ~150us idle (v9). Only plain kernel boundaries are cheap.
//  - clock is FULL during our kernels (v8: VALUBusy 4.4% x 111us == issue-count
//    at 2.35 GHz) -> the v1-v6 time is real work, not downclock.
//  - LDS atomics are CHEAP (v1 9216 lane-ops/CU vs v5 3072: delta 1us).
//  - the dominant cost is per-CU point-EVALS (60 VALU + 6 transcendental each,
//    broadcast-redundant): 32768/CU = 37-39us (v1/v4/v5), 16384/CU -> 34 total
//    (v6, best=75.4 incl 41us harness fill).
// So v10 drives evals/CU to the floor: each point is evaluated by exactly TWO
// blocks (one per 128-row half) -> evals/CU = 2048.
//
// gh_part: block = (batch 8) x (chunk 32 of 1024 pts) x (row-half 2) = 512
// blocks, 1024 thr, 64 KB LDS = single-phase 16-bit-packed [128 rows][64
// words] tile (4 cols per u64 word). One point per thread: 3 exact row taps x
// 3 exact col taps (same math as v1/v4/v5/v6, all passed absmax 0.0156).
// Col window [j0-1,j0+1] lands in word (c0>>2) at field offset (c0&3);
// branchless funnel-shift splits the 3 packed fields into (lo, hi) words;
// hi-atomic only when nonzero (~50% of taps). Deposits only for rows in the
// block's half. Partial tile -> ws (plain coalesced store, 32 MB total).
// gh_reduce: out[cell] = sum over 32 chunks of the cell's 16-bit field,
// accumulated FIELDWISE in u32 (no cross-field carry by construction),
// * 1/1024. Reads 32 MB (L3-resident), writes 2 MB = full d_out overwrite.
//
// Overflow: field sum over a full batch = cell mass * 1024 ~ 256 avg, < 65535
// for any remotely uniform data (and u32 accumulators in reduce are exact).
// Fixed-point noise ~1e-3 vs 8.6e-2 threshold.

#define BINS   256
#define NPTS   32768
#define BATCH  8
#define CHUNK  32                  // point chunks per batch
#define PPB    (NPTS / CHUNK)      // 1024 points per chunk
#define HROWS  128                 // rows per half-tile
#define WROW   64                  // u64 words per row (4 cols each)
#define TILE64 (HROWS * WROW)      // 8192 u64 = 64 KB
#define NBLK   (BATCH * CHUNK * 2) // 512 blocks

static constexpr float kInvDelta = 256.0f / 1.5f;                  // 1/DELTA
static constexpr float kUAdd     = 0.25f * (256.0f / 1.5f) - 0.5f; // (x-MIN)/D - 0.5
static constexpr float kPi       = 3.14159265358979323846f;
static constexpr float kTwoPi    = 6.28318530717958647692f;
static constexpr float kEmPi     = 0.043213918263772250f;   // exp(-pi)
static constexpr float kFix      = 1024.0f;                 // .10 fixed point
static constexpr float kInvFix   = 1.0f / 1024.0f;

__global__ __launch_bounds__(1024) void gh_part(
    const float* __restrict__ x1, const float* __restrict__ x2,
    const float* __restrict__ mask, unsigned long long* __restrict__ ws)
{
    __shared__ unsigned long long lds[TILE64];   // 64 KB
    const int tid = threadIdx.x;
    const int h   = blockIdx.x & 1;              // row half
    const int z   = (blockIdx.x >> 1) & 31;      // chunk
    const int b   = blockIdx.x >> 6;             // batch
    const int rb  = h * HROWS;                   // first owned row

#pragma unroll
    for (int i = tid; i < TILE64; i += 1024) lds[i] = 0ULL;
    __syncthreads();

    // one point per thread
    const int n = b * NPTS + z * PPB + tid;
    const float xv = x1[n];
    const float yv = x2[n];
    const float mv = mask[n];

    const float u1 = fmaf(xv, kInvDelta, kUAdd);
    const float u2 = fmaf(yv, kInvDelta, kUAdd);
    int i0 = (int)rintf(u1); i0 = min(254, max(1, i0));
    int j0 = (int)rintf(u2); j0 = min(252, max(1, j0));   // word+1 <= 63 safe
    const float t1 = u1 - (float)i0;             // [-0.5, 0.5] in-spec
    const float t2 = u2 - (float)j0;

    // factored weights: w(0)=w0, w(-/+1) = w0*K*G^{+/-1}, G=e^{-2pi t}, K=e^{-pi}
    const float w0  = __expf(-kPi * t1 * t1);
    const float G1  = __expf(-kTwoPi * t1);
    const float iG1 = __builtin_amdgcn_rcpf(G1);
    const float w0K = w0 * kEmPi;
    const float wr[3] = { w0K * G1, w0, w0K * iG1 };

    const float vc  = __expf(-kPi * t2 * t2) * (mv * kFix);
    const float G2  = __expf(-kTwoPi * t2);
    const float iG2 = __builtin_amdgcn_rcpf(G2);
    const float vcK = vc * kEmPi;
    const float v0 = vcK * G2, v1 = vc, v2 = vcK * iG2;  // cols j0-1, j0, j0+1

    const int c0   = j0 - 1;
    const int word = c0 >> 2;
    const int sh   = 16 * (c0 & 3);

#pragma unroll
    for (int a = 0; a < 3; ++a) {
        const int rloc = i0 - 1 + a - rb;        // row tap, half-local
        if ((unsigned)rloc < HROWS) {
            const float wa = wr[a];
            const unsigned f0 = (unsigned)fmaf(wa, v0, 0.5f);
            const unsigned f1 = (unsigned)fmaf(wa, v1, 0.5f);
            const unsigned f2 = (unsigned)fmaf(wa, v2, 0.5f);
            const unsigned long long q =
                (unsigned long long)f0 | ((unsigned long long)f1 << 16)
                                       | ((unsigned long long)f2 << 32);
            const unsigned long long lo = q << sh;           // fields in word
            const unsigned long long hi = (q >> 1) >> (63 - sh); // spill word+1
            atomicAdd(&lds[rloc * WROW + word], lo);         // ds_add_u64
            if (hi) atomicAdd(&lds[rloc * WROW + word + 1], hi);
        }
    }
    __syncthreads();

    // plain coalesced store of the 64 KB partial (zeros included)
    unsigned long long* W = ws + (size_t)blockIdx.x * TILE64;
#pragma unroll
    for (int i = tid; i < TILE64; i += 1024) W[i] = lds[i];
}

// out[b,row,4w..4w+3] = sum_z fields of ws[(b,z,row>>7)][(row&127)*64 + w]
__global__ __launch_bounds__(512) void gh_reduce(
    const unsigned long long* __restrict__ ws, float* __restrict__ out)
{
    const int wp  = blockIdx.x * 512 + threadIdx.x;  // word-position, 131072
    const int b   = wp >> 14;              // 16384 words per batch
    const int w   = wp & 16383;
    const int row = w >> 6;
    const int h   = row >> 7;
    const int wl  = (row & (HROWS - 1)) * WROW + (w & 63);

    unsigned s0 = 0, s1 = 0, s2 = 0, s3 = 0;
#pragma unroll
    for (int z = 0; z < CHUNK; ++z) {
        const unsigned long long v =
            ws[(size_t)(((b * CHUNK + z) << 1) + h) * TILE64 + wl];
        s0 += (unsigned)v & 0xFFFFu;
        s1 += (unsigned)(v >> 16) & 0xFFFFu;
        s2 += (unsigned)(v >> 32) & 0xFFFFu;
        s3 += (unsigned)(v >> 48);
    }
    float4 o;
    o.x = (float)s0 * kInvFix;
    o.y = (float)s1 * kInvFix;
    o.z = (float)s2 * kInvFix;
    o.w = (float)s3 * kInvFix;
    ((float4*)out)[wp] = o;                  // cell = 4*wp .. 4*wp+3, coalesced
}

extern "C" void kernel_launch(void* const* d_in, const int* in_sizes, int n_in,
                              void* d_out, int out_size, void* d_ws, size_t ws_size,
                              hipStream_t stream) {
    const float* x1   = (const float*)d_in[0];
    const float* x2   = (const float*)d_in[1];
    const float* mask = (const float*)d_in[2];
    float*       out  = (float*)d_out;
    unsigned long long* ws = (unsigned long long*)d_ws;

    gh_part  <<<dim3(NBLK), 1024, 0, stream>>>(x1, x2, mask, ws);
    gh_reduce<<<dim3(BATCH * BINS * WROW / 512), 512, 0, stream>>>(ws, out);
}